// Round 1
// baseline (240.943 us; speedup 1.0000x reference)
//
#include <hip/hip_runtime.h>
#include <math.h>

#define FL_ALPHA 0.2f
#define FL_EPS   1e-8f

constexpr int C = 20;   // classes
constexpr int M = 32;   // max GT per image

// d_ws layout: per image b: [b*4+0]=cls_sum, [b*4+1]=reg_sum, [b*4+2]=num_pos
__global__ __launch_bounds__(256) void focal_main(
    const float* __restrict__ cls,   // [B,A,C]
    const float* __restrict__ reg,   // [B,A,4]
    const float* __restrict__ anc,   // [A,4]  (anchors[0])
    const float* __restrict__ ann,   // [B,M,5]
    float* __restrict__ ws,
    int A)
{
    __shared__ float s_ann[M * 5];
    __shared__ float s_area[M];
    __shared__ float s_red[4 * 3];   // 4 waves x {cls,reg,pos}

    const int b   = blockIdx.y;
    const int tid = threadIdx.x;

    if (tid < M * 5) s_ann[tid] = ann[(size_t)b * M * 5 + tid];
    __syncthreads();
    if (tid < M) {
        const float gx1 = s_ann[tid*5+0], gy1 = s_ann[tid*5+1];
        const float gx2 = s_ann[tid*5+2], gy2 = s_ann[tid*5+3];
        s_area[tid] = (gx2 - gx1) * (gy2 - gy1);
    }
    __syncthreads();

    const int a = blockIdx.x * 256 + tid;

    float clsSum = 0.f, regSum = 0.f, posf = 0.f;

    if (a < A) {
        const float4 av = *(const float4*)(anc + (size_t)a * 4);
        const float aw  = av.z - av.x;
        const float ah  = av.w - av.y;
        const float acx = av.x + 0.5f * aw;
        const float acy = av.y + 0.5f * ah;
        const float area_a = aw * ah;

        // ---- IoU max / argmax over M GT (LDS broadcast reads) ----
        float iou_max = -2.0f;
        int   arg     = 0;
        #pragma unroll
        for (int j = 0; j < M; ++j) {
            const float gx1 = s_ann[j*5+0], gy1 = s_ann[j*5+1];
            const float gx2 = s_ann[j*5+2], gy2 = s_ann[j*5+3];
            const float gl  = s_ann[j*5+4];
            float iou = -1.0f;
            if (gl != -1.0f) {
                float iw = fminf(av.z, gx2) - fmaxf(av.x, gx1);
                iw = fmaxf(iw, 0.f);
                float ih = fminf(av.w, gy2) - fmaxf(av.y, gy1);
                ih = fmaxf(ih, 0.f);
                const float inter = iw * ih;
                const float ua = fmaxf(area_a + s_area[j] - inter, FL_EPS);
                iou = __fdividef(inter, ua);
            }
            if (iou > iou_max) { iou_max = iou; arg = j; }  // first-occurrence argmax
        }

        const bool pos    = iou_max >= 0.5f;
        const bool ignore = (iou_max >= 0.4f) && !pos;
        const int  lbl    = (int)s_ann[arg*5+4];

        // ---- classification focal loss (skip ignore-band anchors) ----
        if (!ignore) {
            const float* cp = cls + ((size_t)b * A + a) * C;
            #pragma unroll
            for (int k = 0; k < C / 4; ++k) {
                const float4 v = *(const float4*)(cp + k * 4);
                const float pv[4] = {v.x, v.y, v.z, v.w};
                #pragma unroll
                for (int u = 0; u < 4; ++u) {
                    const int c = k * 4 + u;
                    float p = fminf(fmaxf(pv[u], FL_EPS), 1.0f - FL_EPS);
                    const float q  = 1.0f - p;
                    const bool t1  = pos && (c == lbl);
                    const float pe = t1 ? q : p;          // focal-modulation prob
                    const float po = t1 ? p : q;          // prob inside the log
                    const float w  = t1 ? FL_ALPHA : (1.0f - FL_ALPHA);
                    // pe^1.5 == pe*sqrt(pe) exactly (GAMMA = 1.5)
                    clsSum += w * pe * sqrtf(pe) * (-__logf(po));
                }
            }
        }

        // ---- regression smooth-L1 (positives only) ----
        if (pos) {
            posf = 1.0f;
            const float gx1 = s_ann[arg*5+0], gy1 = s_ann[arg*5+1];
            const float gx2 = s_ann[arg*5+2], gy2 = s_ann[arg*5+3];
            const float gwr = gx2 - gx1, ghr = gy2 - gy1;
            const float gcx = gx1 + 0.5f * gwr, gcy = gy1 + 0.5f * ghr;
            const float gw  = fmaxf(gwr, 1.0f), gh = fmaxf(ghr, 1.0f);
            float rt[4];
            rt[0] = ((gcx - acx) / aw) / 0.1f;
            rt[1] = ((gcy - acy) / ah) / 0.1f;
            rt[2] = __logf(gw / aw) / 0.2f;
            rt[3] = __logf(gh / ah) / 0.2f;
            const float4 rv = *(const float4*)(reg + ((size_t)b * A + a) * 4);
            const float rr[4] = {rv.x, rv.y, rv.z, rv.w};
            #pragma unroll
            for (int u = 0; u < 4; ++u) {
                const float d = fabsf(rt[u] - rr[u]);
                regSum += (d <= (float)(1.0 / 9.0)) ? (4.5f * d * d)
                                                    : (d - (float)(0.5 / 9.0));
            }
        }
    }

    // ---- reduce: wave shuffle, then cross-wave LDS, then 3 atomics/block ----
    #pragma unroll
    for (int off = 32; off > 0; off >>= 1) {
        clsSum += __shfl_down(clsSum, off, 64);
        regSum += __shfl_down(regSum, off, 64);
        posf   += __shfl_down(posf,   off, 64);
    }
    const int wave = tid >> 6;
    const int lane = tid & 63;
    if (lane == 0) {
        s_red[wave*3+0] = clsSum;
        s_red[wave*3+1] = regSum;
        s_red[wave*3+2] = posf;
    }
    __syncthreads();
    if (tid == 0) {
        float cs = 0.f, rs = 0.f, ps = 0.f;
        #pragma unroll
        for (int w2 = 0; w2 < 4; ++w2) {
            cs += s_red[w2*3+0];
            rs += s_red[w2*3+1];
            ps += s_red[w2*3+2];
        }
        atomicAdd(&ws[b*4+0], cs);
        atomicAdd(&ws[b*4+1], rs);
        atomicAdd(&ws[b*4+2], ps);
    }
}

__global__ void focal_final(const float* __restrict__ ws,
                            const float* __restrict__ ann,
                            float* __restrict__ out, int B)
{
    if (threadIdx.x == 0 && blockIdx.x == 0) {
        float ca = 0.f, ra = 0.f;
        for (int b = 0; b < B; ++b) {
            int nv = 0;
            for (int j = 0; j < M; ++j)
                nv += (ann[(size_t)b*M*5 + j*5 + 4] != -1.0f) ? 1 : 0;
            const float S  = ws[b*4+0];
            const float R  = ws[b*4+1];
            const float np = ws[b*4+2];
            float cl = S / fmaxf(np, 1.0f);
            float rl = R / fmaxf(4.0f * np, 1.0f);
            if (np <= 0.f) rl = 0.f;
            if (nv == 0) { cl = 0.f; rl = 0.f; }
            ca += cl; ra += rl;
        }
        out[0] = ca / (float)B;
        out[1] = ra / (float)B;
    }
}

extern "C" void kernel_launch(void* const* d_in, const int* in_sizes, int n_in,
                              void* d_out, int out_size, void* d_ws, size_t ws_size,
                              hipStream_t stream) {
    const float* cls = (const float*)d_in[0];   // [B,A,C]
    const float* reg = (const float*)d_in[1];   // [B,A,4]
    const float* anc = (const float*)d_in[2];   // [1,A,4]
    const float* ann = (const float*)d_in[3];   // [B,M,5]
    const int A = in_sizes[2] / 4;
    const int B = in_sizes[3] / (M * 5);
    float* ws = (float*)d_ws;

    // d_ws is re-poisoned to 0xAA before every launch — zero the accumulators.
    hipMemsetAsync(d_ws, 0, (size_t)B * 4 * sizeof(float), stream);

    dim3 grid((A + 255) / 256, B);
    focal_main<<<grid, dim3(256), 0, stream>>>(cls, reg, anc, ann, ws, A);
    focal_final<<<1, 64, 0, stream>>>(ws, ann, (float*)d_out, B);
}

// Round 6
// 232.467 us; speedup vs baseline: 1.0365x; 1.0365x over previous
//
#include <hip/hip_runtime.h>
#include <math.h>

#define FL_ALPHA 0.2f
#define FL_EPS   1e-8f

constexpr int C = 20;   // classes
constexpr int M = 32;   // max GT per image

// d_ws layout: per image b: [b*4+0]=cls_sum, [b*4+1]=reg_sum, [b*4+2]=num_pos
__global__ __launch_bounds__(256) void focal_main(
    const float* __restrict__ cls,   // [B,A,C]
    const float* __restrict__ reg,   // [B,A,4]
    const float* __restrict__ anc,   // [A,4]  (anchors[0])
    const float* __restrict__ ann,   // [B,M,5]
    float* __restrict__ ws,
    int A)
{
    __shared__ float s_ann[M * 5];
    __shared__ float s_area[M];
    __shared__ float s_red[4 * 3];   // 4 waves x {cls,reg,pos}

    const int b   = blockIdx.y;
    const int tid = threadIdx.x;

    if (tid < M * 5) s_ann[tid] = ann[(size_t)b * M * 5 + tid];
    __syncthreads();
    if (tid < M) {
        const float gx1 = s_ann[tid*5+0], gy1 = s_ann[tid*5+1];
        const float gx2 = s_ann[tid*5+2], gy2 = s_ann[tid*5+3];
        s_area[tid] = (gx2 - gx1) * (gy2 - gy1);
    }
    __syncthreads();

    const int a = blockIdx.x * 256 + tid;

    float clsSum = 0.f, regSum = 0.f, posf = 0.f;

    if (a < A) {
        const float4 av = *(const float4*)(anc + (size_t)a * 4);
        const float aw  = av.z - av.x;
        const float ah  = av.w - av.y;
        const float acx = av.x + 0.5f * aw;
        const float acy = av.y + 0.5f * ah;
        const float area_a = aw * ah;

        // ---- IoU max / argmax over M GT (LDS broadcast reads) ----
        float iou_max = -2.0f;
        int   arg     = 0;
        #pragma unroll
        for (int j = 0; j < M; ++j) {
            const float gx1 = s_ann[j*5+0], gy1 = s_ann[j*5+1];
            const float gx2 = s_ann[j*5+2], gy2 = s_ann[j*5+3];
            const float gl  = s_ann[j*5+4];
            float iou = -1.0f;
            if (gl != -1.0f) {
                float iw = fminf(av.z, gx2) - fmaxf(av.x, gx1);
                iw = fmaxf(iw, 0.f);
                float ih = fminf(av.w, gy2) - fmaxf(av.y, gy1);
                ih = fmaxf(ih, 0.f);
                const float inter = iw * ih;
                const float ua = fmaxf(area_a + s_area[j] - inter, FL_EPS);
                iou = __fdividef(inter, ua);
            }
            if (iou > iou_max) { iou_max = iou; arg = j; }  // first-occurrence argmax
        }

        const bool pos    = iou_max >= 0.5f;
        const bool ignore = (iou_max >= 0.4f) && !pos;
        const int  lbl    = (int)s_ann[arg*5+4];

        // ---- classification focal loss (skip ignore-band anchors) ----
        if (!ignore) {
            const float* cp = cls + ((size_t)b * A + a) * C;
            #pragma unroll
            for (int k = 0; k < C / 4; ++k) {
                const float4 v = *(const float4*)(cp + k * 4);
                const float pv[4] = {v.x, v.y, v.z, v.w};
                #pragma unroll
                for (int u = 0; u < 4; ++u) {
                    const int c = k * 4 + u;
                    float p = fminf(fmaxf(pv[u], FL_EPS), 1.0f - FL_EPS);
                    const float q  = 1.0f - p;
                    const bool t1  = pos && (c == lbl);
                    const float pe = t1 ? q : p;          // focal-modulation prob
                    const float po = t1 ? p : q;          // prob inside the log
                    const float w  = t1 ? FL_ALPHA : (1.0f - FL_ALPHA);
                    // pe^1.5 == pe*sqrt(pe) exactly (GAMMA = 1.5)
                    clsSum += w * pe * sqrtf(pe) * (-__logf(po));
                }
            }
        }

        // ---- regression smooth-L1 (positives only) ----
        if (pos) {
            posf = 1.0f;
            const float gx1 = s_ann[arg*5+0], gy1 = s_ann[arg*5+1];
            const float gx2 = s_ann[arg*5+2], gy2 = s_ann[arg*5+3];
            const float gwr = gx2 - gx1, ghr = gy2 - gy1;
            const float gcx = gx1 + 0.5f * gwr, gcy = gy1 + 0.5f * ghr;
            const float gw  = fmaxf(gwr, 1.0f), gh = fmaxf(ghr, 1.0f);
            float rt[4];
            rt[0] = ((gcx - acx) / aw) / 0.1f;
            rt[1] = ((gcy - acy) / ah) / 0.1f;
            rt[2] = __logf(gw / aw) / 0.2f;
            rt[3] = __logf(gh / ah) / 0.2f;
            const float4 rv = *(const float4*)(reg + ((size_t)b * A + a) * 4);
            const float rr[4] = {rv.x, rv.y, rv.z, rv.w};
            #pragma unroll
            for (int u = 0; u < 4; ++u) {
                const float d = fabsf(rt[u] - rr[u]);
                regSum += (d <= (float)(1.0 / 9.0)) ? (4.5f * d * d)
                                                    : (d - (float)(0.5 / 9.0));
            }
        }
    }

    // ---- reduce: wave shuffle, then cross-wave LDS, then 3 atomics/block ----
    #pragma unroll
    for (int off = 32; off > 0; off >>= 1) {
        clsSum += __shfl_down(clsSum, off, 64);
        regSum += __shfl_down(regSum, off, 64);
        posf   += __shfl_down(posf,   off, 64);
    }
    const int wave = tid >> 6;
    const int lane = tid & 63;
    if (lane == 0) {
        s_red[wave*3+0] = clsSum;
        s_red[wave*3+1] = regSum;
        s_red[wave*3+2] = posf;
    }
    __syncthreads();
    if (tid == 0) {
        float cs = 0.f, rs = 0.f, ps = 0.f;
        #pragma unroll
        for (int w2 = 0; w2 < 4; ++w2) {
            cs += s_red[w2*3+0];
            rs += s_red[w2*3+1];
            ps += s_red[w2*3+2];
        }
        atomicAdd(&ws[b*4+0], cs);
        atomicAdd(&ws[b*4+1], rs);
        atomicAdd(&ws[b*4+2], ps);
    }
}

// Finalize: 256 threads load all (b,gt) validity flags in parallel (the R1
// version did 280 dependent global loads in one thread == ~105 us).
__global__ __launch_bounds__(256) void focal_final(
    const float* __restrict__ ws,
    const float* __restrict__ ann,
    float* __restrict__ out, int B)
{
    __shared__ float s_f[256];
    __shared__ float s_c[8], s_r[8];
    const int tid = threadIdx.x;

    float f = 0.f;
    if (tid < B * M) {
        const int bb = tid >> 5, j = tid & 31;
        f = (ann[(size_t)bb * M * 5 + (size_t)j * 5 + 4] != -1.0f) ? 1.f : 0.f;
    }
    s_f[tid] = f;
    __syncthreads();

    if (tid < B) {
        float nv = 0.f;
        #pragma unroll
        for (int j = 0; j < M; ++j) nv += s_f[tid * M + j];
        const float S  = ws[tid * 4 + 0];
        const float R  = ws[tid * 4 + 1];
        const float np = ws[tid * 4 + 2];
        float cl = S / fmaxf(np, 1.f);
        float rl = (np > 0.f) ? R / fmaxf(4.f * np, 1.f) : 0.f;
        if (nv == 0.f) { cl = 0.f; rl = 0.f; }
        s_c[tid] = cl; s_r[tid] = rl;
    }
    __syncthreads();

    if (tid == 0) {
        float ca = 0.f, ra = 0.f;
        for (int b2 = 0; b2 < B; ++b2) { ca += s_c[b2]; ra += s_r[b2]; }
        out[0] = ca / (float)B;
        out[1] = ra / (float)B;
    }
}

extern "C" void kernel_launch(void* const* d_in, const int* in_sizes, int n_in,
                              void* d_out, int out_size, void* d_ws, size_t ws_size,
                              hipStream_t stream) {
    const float* cls = (const float*)d_in[0];   // [B,A,C]
    const float* reg = (const float*)d_in[1];   // [B,A,4]
    const float* anc = (const float*)d_in[2];   // [1,A,4]
    const float* ann = (const float*)d_in[3];   // [B,M,5]
    const int A = in_sizes[2] / 4;
    const int B = in_sizes[3] / (M * 5);
    float* ws = (float*)d_ws;

    // d_ws is re-poisoned to 0xAA before every launch — zero the accumulators.
    hipMemsetAsync(d_ws, 0, (size_t)B * 4 * sizeof(float), stream);

    dim3 grid((A + 255) / 256, B);
    focal_main<<<grid, dim3(256), 0, stream>>>(cls, reg, anc, ann, ws, A);
    focal_final<<<1, dim3(256), 0, stream>>>(ws, ann, (float*)d_out, B);
}

// Round 7
// 217.090 us; speedup vs baseline: 1.1099x; 1.0708x over previous
//
#include <hip/hip_runtime.h>
#include <math.h>

constexpr int C = 20;   // classes
constexpr int M = 32;   // max GT per image

// d_ws layout: per image b: [b*4+0]=cls_sum, [b*4+1]=reg_sum, [b*4+2]=num_pos
__global__ __launch_bounds__(256) void focal_main(
    const float* __restrict__ cls,   // [B,A,C]
    const float* __restrict__ reg,   // [B,A,4]
    const float* __restrict__ anc,   // [A,4]
    const float* __restrict__ ann,   // [B,M,5]
    float* __restrict__ ws,
    int A)
{
    __shared__ float4 s_gbox[M];   // {x1,y1,x2,y2}; invalid GT -> zero box (iou=0)
    __shared__ float  s_garea[M];
    __shared__ int    s_glbl[M];
    __shared__ float  s_red[4 * 3];

    const int b   = blockIdx.y;
    const int tid = threadIdx.x;
    const int a   = blockIdx.x * 256 + tid;
    const bool live  = a < A;
    const int  asafe = live ? a : 0;

    // ---- issue ALL global loads first; LDS staging + IoU loop hide latency ----
    const float4 av = *(const float4*)(anc + (size_t)asafe * 4);
    const float* cp = cls + ((size_t)b * A + asafe) * C;
    const float4 c0 = *(const float4*)(cp + 0);
    const float4 c1 = *(const float4*)(cp + 4);
    const float4 c2 = *(const float4*)(cp + 8);
    const float4 c3 = *(const float4*)(cp + 12);
    const float4 c4 = *(const float4*)(cp + 16);
    const float4 rv = *(const float4*)(reg + ((size_t)b * A + asafe) * 4);

    // ---- stage annotations into LDS (validity folded into the box) ----
    if (tid < M) {
        const float* ap = ann + (size_t)b * M * 5 + (size_t)tid * 5;
        float x1 = ap[0], y1 = ap[1], x2 = ap[2], y2 = ap[3];
        const float lb = ap[4];
        s_glbl[tid] = (int)lb;
        if (lb == -1.0f) { x1 = 0.f; y1 = 0.f; x2 = 0.f; y2 = 0.f; }
        s_gbox[tid]  = make_float4(x1, y1, x2, y2);
        s_garea[tid] = (x2 - x1) * (y2 - y1);
    }
    __syncthreads();

    const float aw  = av.z - av.x;
    const float ah  = av.w - av.y;
    const float acx = av.x + 0.5f * aw;
    const float acy = av.y + 0.5f * ah;
    const float area_a = aw * ah;

    // ---- IoU max / argmax over M GT (2 broadcast LDS reads/iter) ----
    float bv = -1.0f;
    int   bi = 0;
    #pragma unroll
    for (int j = 0; j < M; ++j) {
        const float4 g  = s_gbox[j];
        const float  ab = s_garea[j];
        const float iw = fmaxf(fminf(av.z, g.z) - fmaxf(av.x, g.x), 0.f);
        const float ih = fmaxf(fminf(av.w, g.w) - fmaxf(av.y, g.y), 0.f);
        const float inter = iw * ih;
        const float ua = fmaxf(area_a + ab - inter, 1e-8f);
        const float iou = __fdividef(inter, ua);
        if (iou > bv) { bv = iou; bi = j; }   // first-occurrence argmax
    }

    const bool pos    = bv >= 0.5f;
    const bool ignore = (bv >= 0.4f) && !pos;
    const int  lbl    = s_glbl[bi];           // only meaningful when pos (valid GT)

    // ---- classification focal loss (branchless; mask ignore/dead at end) ----
    float pv[C];
    pv[0]=c0.x;  pv[1]=c0.y;  pv[2]=c0.z;  pv[3]=c0.w;
    pv[4]=c1.x;  pv[5]=c1.y;  pv[6]=c1.z;  pv[7]=c1.w;
    pv[8]=c2.x;  pv[9]=c2.y;  pv[10]=c2.z; pv[11]=c2.w;
    pv[12]=c3.x; pv[13]=c3.y; pv[14]=c3.z; pv[15]=c3.w;
    pv[16]=c4.x; pv[17]=c4.y; pv[18]=c4.z; pv[19]=c4.w;

    float clsSum = 0.f;
    #pragma unroll
    for (int c = 0; c < C; ++c) {
        const float p  = fminf(fmaxf(pv[c], 1e-8f), 1.0f - 1e-8f);
        const float q  = 1.0f - p;
        const bool  t1 = pos && (c == lbl);
        const float pe = t1 ? q : p;               // focal-modulation prob
        const float po = t1 ? p : q;               // prob inside the log
        const float w  = t1 ? 0.2f : 0.8f;
        // pe^1.5 == pe*sqrt(pe) exactly (gamma=1.5); raw v_sqrt_f32 is 1-ulp
        clsSum += w * pe * __builtin_amdgcn_sqrtf(pe) * (-__logf(po));
    }
    clsSum = (ignore || !live) ? 0.f : clsSum;

    // ---- regression smooth-L1 (positives only; R1's exact arithmetic) ----
    float regSum = 0.f, posf = 0.f;
    if (pos && live) {
        posf = 1.f;
        const float4 g = s_gbox[bi];
        const float gwr = g.z - g.x, ghr = g.w - g.y;
        const float gcx = g.x + 0.5f * gwr, gcy = g.y + 0.5f * ghr;
        const float gw = fmaxf(gwr, 1.f), gh = fmaxf(ghr, 1.f);
        float rt[4];
        rt[0] = ((gcx - acx) / aw) / 0.1f;
        rt[1] = ((gcy - acy) / ah) / 0.1f;
        rt[2] = __logf(gw / aw) / 0.2f;
        rt[3] = __logf(gh / ah) / 0.2f;
        const float rr[4] = {rv.x, rv.y, rv.z, rv.w};
        #pragma unroll
        for (int u = 0; u < 4; ++u) {
            const float d = fabsf(rt[u] - rr[u]);
            regSum += (d <= (float)(1.0 / 9.0)) ? (4.5f * d * d)
                                                : (d - (float)(0.5 / 9.0));
        }
    }

    // ---- reduce: wave shuffle -> cross-wave LDS -> 3 atomics/block ----
    #pragma unroll
    for (int off = 32; off > 0; off >>= 1) {
        clsSum += __shfl_down(clsSum, off, 64);
        regSum += __shfl_down(regSum, off, 64);
        posf   += __shfl_down(posf,   off, 64);
    }
    const int wave = tid >> 6;
    const int lane = tid & 63;
    if (lane == 0) {
        s_red[wave * 3 + 0] = clsSum;
        s_red[wave * 3 + 1] = regSum;
        s_red[wave * 3 + 2] = posf;
    }
    __syncthreads();
    if (tid == 0) {
        float cs = 0.f, rs = 0.f, ps = 0.f;
        #pragma unroll
        for (int w2 = 0; w2 < 4; ++w2) {
            cs += s_red[w2 * 3 + 0];
            rs += s_red[w2 * 3 + 1];
            ps += s_red[w2 * 3 + 2];
        }
        atomicAdd(&ws[b * 4 + 0], cs);
        atomicAdd(&ws[b * 4 + 1], rs);
        atomicAdd(&ws[b * 4 + 2], ps);
    }
}

// Finalize: 256 threads load all (b,gt) validity flags in parallel.
__global__ __launch_bounds__(256) void focal_final(
    const float* __restrict__ ws,
    const float* __restrict__ ann,
    float* __restrict__ out, int B)
{
    __shared__ float s_f[256];
    __shared__ float s_c[8], s_r[8];
    const int tid = threadIdx.x;

    float f = 0.f;
    if (tid < B * M) {
        const int bb = tid >> 5, j = tid & 31;
        f = (ann[(size_t)bb * M * 5 + (size_t)j * 5 + 4] != -1.0f) ? 1.f : 0.f;
    }
    s_f[tid] = f;
    __syncthreads();

    if (tid < B) {
        float nv = 0.f;
        #pragma unroll
        for (int j = 0; j < M; ++j) nv += s_f[tid * M + j];
        const float S  = ws[tid * 4 + 0];
        const float R  = ws[tid * 4 + 1];
        const float np = ws[tid * 4 + 2];
        float cl = S / fmaxf(np, 1.f);
        float rl = (np > 0.f) ? R / fmaxf(4.f * np, 1.f) : 0.f;
        if (nv == 0.f) { cl = 0.f; rl = 0.f; }
        s_c[tid] = cl; s_r[tid] = rl;
    }
    __syncthreads();

    if (tid == 0) {
        float ca = 0.f, ra = 0.f;
        for (int b2 = 0; b2 < B; ++b2) { ca += s_c[b2]; ra += s_r[b2]; }
        out[0] = ca / (float)B;
        out[1] = ra / (float)B;
    }
}

extern "C" void kernel_launch(void* const* d_in, const int* in_sizes, int n_in,
                              void* d_out, int out_size, void* d_ws, size_t ws_size,
                              hipStream_t stream) {
    const float* cls = (const float*)d_in[0];   // [B,A,C]
    const float* reg = (const float*)d_in[1];   // [B,A,4]
    const float* anc = (const float*)d_in[2];   // [1,A,4]
    const float* ann = (const float*)d_in[3];   // [B,M,5]
    const int A = in_sizes[2] / 4;
    const int B = in_sizes[3] / (M * 5);
    float* ws = (float*)d_ws;

    // d_ws is re-poisoned to 0xAA before every launch — zero the accumulators.
    hipMemsetAsync(d_ws, 0, (size_t)B * 4 * sizeof(float), stream);

    dim3 grid((A + 255) / 256, B);
    focal_main<<<grid, dim3(256), 0, stream>>>(cls, reg, anc, ann, ws, A);
    focal_final<<<1, dim3(256), 0, stream>>>(ws, ann, (float*)d_out, B);
}